// Round 1
// 122.746 us; speedup vs baseline: 1.0006x; 1.0006x over previous
//
#include <hip/hip_runtime.h>
#include <hip/hip_bf16.h>

typedef unsigned short u16;
typedef unsigned int u32;
typedef __attribute__((ext_vector_type(8))) short bf16x8;   // 8 bf16 = 4 VGPR
typedef __attribute__((ext_vector_type(16))) float f32x16;  // 32x32 C/D frag
typedef __attribute__((ext_vector_type(2))) unsigned int u32x2;
typedef _Float16 h16x2 __attribute__((ext_vector_type(2)));

static __device__ __forceinline__ u16 f2bf(float f) {
    __hip_bfloat16 b = __float2bfloat16(f);   // RNE
    return *(u16*)&b;
}
static __device__ __forceinline__ u16 f2h(float f) {
    _Float16 h = (_Float16)f;                  // RNE
    return __builtin_bit_cast(u16, h);
}

// ---------------------------------------------------------------------------
// Kernel 0: build W1's MFMA fragment table (node-independent) + W2 as fp16.
// wtab flat index = ((ct*4 + ks)*64 + lane)*8 + j  holds (bf16)
//   Wcat[k = ks*16 + (lane>>5)*8 + j][c = ct*32 + (lane&31)]
// This same layout serves as the *A*-fragment (M = c) for the swapped-operand
// MFMA in node_mfma below: A[m=lane&31][k=(lane>>5)*8+j] = Wcat[k][ct*32+m].
// w2tab (64 fp16 at wtab+8192) saves the per-thread f32->f16 W2 conversion
// in edge_mlp (loaded L1-hot as uint4).
// ---------------------------------------------------------------------------
__global__ __launch_bounds__(256) void build_wfrag(
    const float* __restrict__ W1, const float* __restrict__ W2,
    u16* __restrict__ wtab)
{
    const int flat = blockIdx.x * 256 + threadIdx.x;
    if (flat < 8192) {
        const int j    = flat & 7;
        const int lane = (flat >> 3) & 63;
        const int ks   = (flat >> 9) & 3;
        const int ct   = flat >> 11;
        const int k = ks * 16 + (lane >> 5) * 8 + j;
        const int c = ct * 32 + (lane & 31);
        const float v = (c < 64) ? W1[(size_t)k * 64 + c]
                                 : W1[(size_t)(64 + k) * 64 + (c - 64)];
        wtab[flat] = f2bf(v);
    } else if (flat < 8256) {
        wtab[flat] = f2h(W2[flat - 8192]);     // w2tab
    }
}

// ---------------------------------------------------------------------------
// Kernel A (MFMA, swapped operands): pq[n][c], c in 0..127 (fp16), where
//   c <  64 (P): b1[c] + sum_k z[n][k] * W1[k][c]
//   c >= 64 (Q):         sum_k z[n][k] * W1[64+k][c-64]
// A = Wcat fragment (M = c), B = z fragment (N = node). Same register
// contents as the previous version, arguments swapped. D layout (verified):
//   col  = lane&31            -> node within 32-tile
//   row  = (reg&3)+8*(reg>>2)+4*(lane>>5) -> c within 32-col tile
// so regs 4g..4g+3 are FOUR CONSECUTIVE c values -> pack to 8 B and write to
// a per-wave LDS tile (XOR-swizzled: row stride 256 B would otherwise be a
// 32-way bank conflict), then read back coalesced and store 8x dwordx4/lane
// (1 KB per store instruction) instead of 64x 2-B scattered stores.
// Bias b1 is folded into the accumulator init.
// ---------------------------------------------------------------------------
__global__ __launch_bounds__(256) void node_mfma(
    const float* __restrict__ z, const u16* __restrict__ wtab,
    const float* __restrict__ b1, u16* __restrict__ pq, int nNodes)
{
    const int lane   = threadIdx.x & 63;
    const int wave   = threadIdx.x >> 6;
    const int l31    = lane & 31;
    const int half   = lane >> 5;
    const int nodeBase = (blockIdx.x * 4 + wave) * 32;
    if (nodeBase >= nNodes) return;

    __shared__ u16 tile[4][4096];              // 8 KB per wave, wave-private

    // ---- A fragments: W table, coalesced L2-hot loads
    const bf16x8* wt = (const bf16x8*)wtab;
    bf16x8 Wf[4][4];
#pragma unroll
    for (int ct = 0; ct < 4; ++ct)
#pragma unroll
        for (int ks = 0; ks < 4; ++ks)
            Wf[ct][ks] = wt[(ct * 4 + ks) * 64 + lane];

    // ---- B fragments: Zf[ks][j] = z[nodeBase+l31][ks*16 + half*8 + j]
    int zrowi = nodeBase + l31;
    if (zrowi > nNodes - 1) zrowi = nNodes - 1;       // clamp (safe redundant)
    const float* zrow = z + (size_t)zrowi * 64;
    bf16x8 Zf[4];
#pragma unroll
    for (int ks = 0; ks < 4; ++ks) {
        const float4 v0 = *(const float4*)(zrow + ks * 16 + half * 8);
        const float4 v1 = *(const float4*)(zrow + ks * 16 + half * 8 + 4);
        Zf[ks][0] = (short)f2bf(v0.x); Zf[ks][1] = (short)f2bf(v0.y);
        Zf[ks][2] = (short)f2bf(v0.z); Zf[ks][3] = (short)f2bf(v0.w);
        Zf[ks][4] = (short)f2bf(v1.x); Zf[ks][5] = (short)f2bf(v1.y);
        Zf[ks][6] = (short)f2bf(v1.z); Zf[ks][7] = (short)f2bf(v1.w);
    }

    // ---- accumulators initialized with bias: acc[ct][4g+r] = b1[c],
    //      c = ct*32 + 8g + 4*half + r   (ct<2 = P cols; ct>=2 = Q, zero)
    f32x16 acc[4];
#pragma unroll
    for (int ct = 0; ct < 2; ++ct)
#pragma unroll
        for (int g = 0; g < 4; ++g) {
            const float4 bv = *(const float4*)(b1 + ct * 32 + g * 8 + half * 4);
            acc[ct][4 * g + 0] = bv.x; acc[ct][4 * g + 1] = bv.y;
            acc[ct][4 * g + 2] = bv.z; acc[ct][4 * g + 3] = bv.w;
        }
    acc[2] = (f32x16)(0.0f);
    acc[3] = (f32x16)(0.0f);

    // ---- MFMA accumulate (A = W, B = z)
#pragma unroll
    for (int ks = 0; ks < 4; ++ks)
#pragma unroll
        for (int ct = 0; ct < 4; ++ct)
            acc[ct] = __builtin_amdgcn_mfma_f32_32x32x16_bf16(
                Wf[ct][ks], Zf[ks], acc[ct], 0, 0, 0);

    // ---- epilogue phase 1: pack 4 consecutive c -> 8 B, swizzled ds_write_b64
    // LDS logical layout: tile[wave] = [node 0..31][c 0..127] fp16 (256 B rows)
    // swizzle: byte_off_in_row ^= (node&7)<<4  (bijective, kills the 32-way
    // stride-256B bank conflict; bit 3 (half*8) untouched so 8 B writes stay
    // intact).  Wave-private tile + in-order per-wave LDS => no barrier.
    char* tb = (char*)&tile[wave][0];
#pragma unroll
    for (int ct = 0; ct < 4; ++ct)
#pragma unroll
        for (int g = 0; g < 4; ++g) {
            const u32 lo = (u32)f2h(acc[ct][4 * g + 0]) |
                           ((u32)f2h(acc[ct][4 * g + 1]) << 16);
            const u32 hi = (u32)f2h(acc[ct][4 * g + 2]) |
                           ((u32)f2h(acc[ct][4 * g + 3]) << 16);
            const int roff = (ct * 64 + g * 16 + half * 8) ^ ((l31 & 7) << 4);
            *(u32x2*)(tb + l31 * 256 + roff) = (u32x2){lo, hi};
        }

    // ---- epilogue phase 2: coalesced read-back + 1 KB/instr global stores
#pragma unroll
    for (int it = 0; it < 8; ++it) {
        const int c16  = lane + 64 * it;       // 16-B chunk id in 8 KB tile
        const int nd   = c16 >> 4;             // node within tile
        const int roff = ((c16 & 15) * 16) ^ ((nd & 7) << 4);
        const uint4 v = *(const uint4*)(tb + nd * 256 + roff);
        if (nodeBase + nd < nNodes)
            *(uint4*)(pq + (size_t)nodeBase * 128 + (size_t)c16 * 8) = v;
    }
}

// ---------------------------------------------------------------------------
// Kernel B: edge MLP tail. NOW 4 lanes per edge, 4x16-B gathers per thread
// (was 8 lanes / 2 gathers): same bytes, 2x the outstanding gather requests
// per thread, half the waves and half the duplicated index loads — attacks
// the latency-bound gather identified in R6.  W2 comes pre-converted (fp16)
// from wtab+8192.
//   out[e] = b2 + sum_h W2[h] * relu(P[i][h] + Q[j][h])
// ---------------------------------------------------------------------------
__global__ __launch_bounds__(256) void edge_mlp(
    const int* __restrict__ e0, const int* __restrict__ e1,
    const u16* __restrict__ pq, const u16* __restrict__ w2tab,
    const float* __restrict__ b2, float* __restrict__ out, int E)
{
    const int gid = blockIdx.x * 256 + threadIdx.x;
    const int e   = gid >> 2;
    const int sub = gid & 3;
    if (e >= E) return;

    const int i = e0[e];
    const int j = e1[e];

    const uint4* pr = (const uint4*)(pq + (size_t)i * 128);
    const uint4* qr = (const uint4*)(pq + (size_t)j * 128 + 64);
    const uint4 p0 = pr[2 * sub];
    const uint4 p1 = pr[2 * sub + 1];
    const uint4 q0 = qr[2 * sub];
    const uint4 q1 = qr[2 * sub + 1];

    const uint4* wr = (const uint4*)w2tab;     // L1-hot fp16 W2
    const uint4 w0 = wr[2 * sub];
    const uint4 w1 = wr[2 * sub + 1];

    const u32 pw[8] = {p0.x, p0.y, p0.z, p0.w, p1.x, p1.y, p1.z, p1.w};
    const u32 qw[8] = {q0.x, q0.y, q0.z, q0.w, q1.x, q1.y, q1.z, q1.w};
    const u32 ww[8] = {w0.x, w0.y, w0.z, w0.w, w1.x, w1.y, w1.z, w1.w};
    const h16x2 hzero = (h16x2){(_Float16)0.0f, (_Float16)0.0f};

    float sum = 0.0f;
#pragma unroll
    for (int c = 0; c < 8; ++c) {
        h16x2 pp = __builtin_bit_cast(h16x2, pw[c]);
        h16x2 qq = __builtin_bit_cast(h16x2, qw[c]);
        h16x2 wc = __builtin_bit_cast(h16x2, ww[c]);
        h16x2 a  = __builtin_elementwise_max(pp + qq, hzero); // pk_add + pk_max
#if __has_builtin(__builtin_amdgcn_fdot2)
        sum = __builtin_amdgcn_fdot2(a, wc, sum, false);
#else
        sum = fmaf((float)a[0], (float)wc[0],
              fmaf((float)a[1], (float)wc[1], sum));
#endif
    }

    sum += __shfl_xor(sum, 1);
    sum += __shfl_xor(sum, 2);

    if (sub == 0) out[e] = sum + b2[0];
}

// ---------------------------------------------------------------------------
extern "C" void kernel_launch(void* const* d_in, const int* in_sizes, int n_in,
                              void* d_out, int out_size, void* d_ws, size_t ws_size,
                              hipStream_t stream) {
    const float* z  = (const float*)d_in[0];
    const int*   eg = (const int*)d_in[1];
    const float* W1 = (const float*)d_in[2];
    const float* b1 = (const float*)d_in[3];
    const float* W2 = (const float*)d_in[4];
    const float* b2 = (const float*)d_in[5];
    float* out = (float*)d_out;

    const int nNodes = in_sizes[0] / 64;   // 100000
    const int E      = in_sizes[1] / 2;    // 1000000

    u16* wtab = (u16*)d_ws;                        // 16 KB frag table + 128 B W2
    u16* pq   = (u16*)d_ws + 16384;                // nNodes*128*2 = 25.6 MB

    build_wfrag<<<dim3(33), dim3(256), 0, stream>>>(W1, W2, wtab);

    dim3 gA((nNodes + 127) / 128);         // 4 waves x 32 nodes per block
    node_mfma<<<gA, dim3(256), 0, stream>>>(z, wtab, b1, pq, nNodes);

    long long tB = (long long)E * 4;       // 4 threads per edge
    dim3 gB((unsigned)((tB + 255) / 256));
    edge_mlp<<<gB, dim3(256), 0, stream>>>(eg, eg + E, pq, wtab + 8192, b2, out, E);
}